// Round 1
// baseline (2576.533 us; speedup 1.0000x reference)
//
#include <hip/hip_runtime.h>

// ESN reservoir, B=256, T=4096, D=8, U=64, leaky=1.0.
// One wave (64 lanes) per batch sequence; lane u owns state[u].
// W_rec connectivity = 1/64 -> ~1 nonzero per column: compressed column
// (src lane, weight) pairs in registers, cross-lane state pull via __shfl.
// x_proj computed ~8-16 steps ahead from double-buffered float4 input loads
// (fills latency stall slots of the serial tanh chain).

constexpr int T_LEN = 4096;
constexpr int B_N   = 256;
constexpr int D_IN  = 8;
constexpr int U_N   = 64;
constexpr int MAXN  = 12;            // max nnz per column we support (E[nnz]=1, Poisson)
constexpr int GS    = 8;             // timesteps per software-pipeline group
constexpr int NG    = T_LEN / GS;    // 512 groups
constexpr int F4    = GS * D_IN / 4; // 16 float4 input loads per group

__global__ __launch_bounds__(64, 1)
void esn_reservoir(const float* __restrict__ inputs,  // [B,T,D]
                   const float* __restrict__ W_in,    // [D,U]
                   const float* __restrict__ bias,    // [U]
                   const float* __restrict__ W_rec,   // [U,U]
                   float* __restrict__ out)           // [B,T,U]
{
    const int b = blockIdx.x;
    const int u = threadIdx.x;  // 0..63, one unit per lane

    const float* inp  = inputs + (size_t)b * (T_LEN * D_IN);
    float*       outp = out    + (size_t)b * (size_t)(T_LEN * U_N) + u;

    // ---- per-lane constants: W_in column u, bias ----
    float win[D_IN];
#pragma unroll
    for (int d = 0; d < D_IN; ++d) win[d] = W_in[d * U_N + u];
    const float bu = bias[u];

    // ---- build compressed column u of W_rec (one-time, scratch is fine) ----
    int   ts[MAXN]; float tw[MAXN];
#pragma unroll
    for (int j = 0; j < MAXN; ++j) { ts[j] = 0; tw[j] = 0.f; }
    int n = 0;
    for (int k = 0; k < U_N; ++k) {
        float w = W_rec[k * U_N + u];
        if (w != 0.f && n < MAXN) { ts[n] = k; tw[n] = w; ++n; }
    }
    // re-materialize into const-indexed (register-resident) arrays
    int rs[MAXN]; float rw[MAXN];
#pragma unroll
    for (int j = 0; j < MAXN; ++j) { rs[j] = ts[j]; rw[j] = tw[j]; }

    // wave-max nnz -> scalar loop bound (uniform branches are cheap)
    int M = n;
#pragma unroll
    for (int off = 32; off > 0; off >>= 1) {
        int o = __shfl_xor(M, off, 64);
        M = (o > M) ? o : M;
    }
    const int Mu = __builtin_amdgcn_readfirstlane(M);

    float state = 0.f;

    float4 bufA[F4], bufB[F4];
    float  xpc[GS], xpn[GS];

    auto load_group = [&](int g, float4* buf) {
        const float4* p = (const float4*)(inp + (size_t)g * (GS * D_IN));
#pragma unroll
        for (int i = 0; i < F4; ++i) buf[i] = p[i];   // all lanes same addr: L1 broadcast
    };
    auto xp_group = [&](const float4* buf, float* xp) {
#pragma unroll
        for (int s = 0; s < GS; ++s) {
            float4 a = buf[2 * s], c = buf[2 * s + 1];
            float v = bu;
            v = fmaf(a.x, win[0], v); v = fmaf(a.y, win[1], v);
            v = fmaf(a.z, win[2], v); v = fmaf(a.w, win[3], v);
            v = fmaf(c.x, win[4], v); v = fmaf(c.y, win[5], v);
            v = fmaf(c.z, win[6], v); v = fmaf(c.w, win[7], v);
            xp[s] = v;
        }
    };
    auto steps = [&](int g, const float* xp) {
#pragma unroll
        for (int s = 0; s < GS; ++s) {
            float acc = xp[s];
#pragma unroll
            for (int j = 0; j < MAXN; ++j) {
                if (j < Mu) {                          // wave-uniform bound
                    float v = __shfl(state, rs[j], 64);
                    acc = fmaf(rw[j], v, acc);
                }
            }
            // tanh(acc) = 1 - 2/(exp(2*acc)+1); exp(+inf)->th=1, exp(0)->th=-1: robust
            float e  = __expf(2.f * acc);
            float th = 1.f - __fdividef(2.f, e + 1.f);
            state = th;
            outp[(g * GS + s) * U_N] = th;             // coalesced 256B store, fire-and-forget
        }
    };

    // ---- prologue ----
    load_group(0, bufA);
    xp_group(bufA, xpc);       // one-time stall on first loads
    load_group(1, bufB);

    // ---- main loop, unrolled by 2 groups for register double-buffering ----
    for (int g = 0; g < NG; g += 2) {
        int gl0 = (g + 2 < NG) ? g + 2 : g;   // clamped (redundant) tail prefetch
        int gl1 = (g + 3 < NG) ? g + 3 : g;
        load_group(gl0, bufA);
        xp_group(bufB, xpn);
        steps(g, xpc);
        load_group(gl1, bufB);
        xp_group(bufA, xpc);
        steps(g + 1, xpn);
    }
}

extern "C" void kernel_launch(void* const* d_in, const int* in_sizes, int n_in,
                              void* d_out, int out_size, void* d_ws, size_t ws_size,
                              hipStream_t stream) {
    const float* inputs = (const float*)d_in[0];
    const float* W_in   = (const float*)d_in[1];
    const float* bias   = (const float*)d_in[2];
    const float* W_rec  = (const float*)d_in[3];
    float* out = (float*)d_out;
    esn_reservoir<<<dim3(B_N), dim3(U_N), 0, stream>>>(inputs, W_in, bias, W_rec, out);
}

// Round 2
// 1069.580 us; speedup vs baseline: 2.4089x; 2.4089x over previous
//
#include <hip/hip_runtime.h>

// ESN reservoir, B=256, T=4096, D=8, U=64, leaky=1.0.
// Two-phase:
//   Phase A: x_proj = (inputs @ W_in + b) * C  written into d_out (same shape),
//            C = 2*log2(e) so phase B computes tanh(x) = 1 - 2/(exp2(Cx)+1)
//            with no extra multiply on the serial chain.
//   Phase B: one wave per sequence; lane u owns state[u]. Sparse W_rec column
//            (nnz ~Poisson(1), capped 12) as register (byte-lane, C*weight)
//            pairs; cross-lane pull via ds_bpermute. x_proj loads are PER-LANE
//            VMEM (vmcnt) so the bpermute's lgkmcnt wait never drains them
//            (SMEM+DS share lgkmcnt -> wave-uniform loads would couple the
//            prefetch into the serial chain; that was round 1's 10x loss).

constexpr int T_LEN = 4096;
constexpr int B_N   = 256;
constexpr int D_IN  = 8;
constexpr int U_N   = 64;
constexpr int MAXN  = 12;           // max nnz per W_rec column supported
constexpr int GS    = 8;            // timesteps per group (prefetch granule)
constexpr int NG    = T_LEN / GS;   // 512
constexpr float CSC = 2.885390081777927f;  // 2*log2(e)

// ---------------- Phase A: x_proj GEMM (parallel, BW-bound) ----------------
__global__ __launch_bounds__(256)
void xproj_kernel(const float* __restrict__ inputs,  // [B,T,D]
                  const float* __restrict__ W_in,    // [D,U]
                  const float* __restrict__ bias,    // [U]
                  float* __restrict__ out)           // [B,T,U] <- C*(x@W_in+b)
{
    const int u   = threadIdx.x & 63;
    const int grp = threadIdx.x >> 6;                // 0..3
    const long long BT = (long long)B_N * T_LEN;

    float w[D_IN];
#pragma unroll
    for (int d = 0; d < D_IN; ++d) w[d] = W_in[d * U_N + u] * CSC;
    const float bu = bias[u] * CSC;

    const long long stride = (long long)gridDim.x * 4;
    for (long long row = (long long)blockIdx.x * 4 + grp; row < BT; row += stride) {
        const float4* ip = (const float4*)(inputs + row * D_IN);
        float4 a = ip[0], c = ip[1];
        float v = bu;
        v = fmaf(a.x, w[0], v); v = fmaf(a.y, w[1], v);
        v = fmaf(a.z, w[2], v); v = fmaf(a.w, w[3], v);
        v = fmaf(c.x, w[4], v); v = fmaf(c.y, w[5], v);
        v = fmaf(c.z, w[6], v); v = fmaf(c.w, w[7], v);
        out[row * U_N + u] = v;
    }
}

// ---------------- Phase B: serial scan (latency-bound) ----------------
__global__ __launch_bounds__(64, 1)
void esn_scan(const float* __restrict__ W_rec,  // [U,U]
              float* __restrict__ out)          // in: C*x_proj, out: states
{
    const int b = blockIdx.x;
    const int u = threadIdx.x;

    float* p = out + (size_t)b * (size_t)(T_LEN * U_N) + u;

    // ---- compress column u of W_rec; pad with zero weights ----
    int   rsb[MAXN]; float rw[MAXN];
#pragma unroll
    for (int j = 0; j < MAXN; ++j) { rsb[j] = 0; rw[j] = 0.f; }
    int n = 0;
    for (int k = 0; k < U_N; ++k) {
        float w = W_rec[k * U_N + u];
        if (w != 0.f && n < MAXN) { rsb[n] = k << 2; rw[n] = w * CSC; ++n; }
    }
    // wave-max nnz (uniform loop bound for the branchy tail)
    int M = n;
#pragma unroll
    for (int off = 32; off > 0; off >>= 1) {
        int o = __shfl_xor(M, off, 64);
        M = (o > M) ? o : M;
    }
    const int Mu = __builtin_amdgcn_readfirstlane(M);

    float state = 0.f;
    float xc[GS], xn[GS];

    // prologue: load group 0 (per-lane VMEM loads -> vmcnt only)
#pragma unroll
    for (int s = 0; s < GS; ++s) xc[s] = p[s * U_N];

    for (int g = 0; g < NG; ++g) {
        // prefetch next group (clamped tail; redundant reload is harmless)
        const float* pn = p + (size_t)((g + 1 < NG) ? g + 1 : g) * (GS * U_N);
#pragma unroll
        for (int s = 0; s < GS; ++s) xn[s] = pn[s * U_N];

        float* ps = p + (size_t)g * (GS * U_N);
#pragma unroll
        for (int s = 0; s < GS; ++s) {
            float acc = xc[s];
            int st = __float_as_int(state);
            // first 4 sparse terms (covers nearly all columns)
            {
                float t0 = __int_as_float(__builtin_amdgcn_ds_bpermute(rsb[0], st));
                float t1 = __int_as_float(__builtin_amdgcn_ds_bpermute(rsb[1], st));
                float t2 = __int_as_float(__builtin_amdgcn_ds_bpermute(rsb[2], st));
                float t3 = __int_as_float(__builtin_amdgcn_ds_bpermute(rsb[3], st));
                acc = fmaf(rw[0], t0, acc); acc = fmaf(rw[1], t1, acc);
                acc = fmaf(rw[2], t2, acc); acc = fmaf(rw[3], t3, acc);
            }
            if (Mu > 4) {
                float t0 = __int_as_float(__builtin_amdgcn_ds_bpermute(rsb[4], st));
                float t1 = __int_as_float(__builtin_amdgcn_ds_bpermute(rsb[5], st));
                float t2 = __int_as_float(__builtin_amdgcn_ds_bpermute(rsb[6], st));
                float t3 = __int_as_float(__builtin_amdgcn_ds_bpermute(rsb[7], st));
                acc = fmaf(rw[4], t0, acc); acc = fmaf(rw[5], t1, acc);
                acc = fmaf(rw[6], t2, acc); acc = fmaf(rw[7], t3, acc);
            }
            if (Mu > 8) {
                float t0 = __int_as_float(__builtin_amdgcn_ds_bpermute(rsb[8], st));
                float t1 = __int_as_float(__builtin_amdgcn_ds_bpermute(rsb[9], st));
                float t2 = __int_as_float(__builtin_amdgcn_ds_bpermute(rsb[10], st));
                float t3 = __int_as_float(__builtin_amdgcn_ds_bpermute(rsb[11], st));
                acc = fmaf(rw[8], t0, acc); acc = fmaf(rw[9], t1, acc);
                acc = fmaf(rw[10], t2, acc); acc = fmaf(rw[11], t3, acc);
            }
            // acc is already C*x; tanh(x) = 1 - 2/(exp2(C*x)+1)
            float e  = __builtin_amdgcn_exp2f(acc);
            float r  = __builtin_amdgcn_rcpf(e + 1.f);
            float th = fmaf(-2.f, r, 1.f);
            state = th;
            ps[s * U_N] = th;   // coalesced fire-and-forget store (vmcnt)
        }
#pragma unroll
        for (int s = 0; s < GS; ++s) xc[s] = xn[s];
    }
}

extern "C" void kernel_launch(void* const* d_in, const int* in_sizes, int n_in,
                              void* d_out, int out_size, void* d_ws, size_t ws_size,
                              hipStream_t stream) {
    const float* inputs = (const float*)d_in[0];
    const float* W_in   = (const float*)d_in[1];
    const float* bias   = (const float*)d_in[2];
    const float* W_rec  = (const float*)d_in[3];
    float* out = (float*)d_out;

    xproj_kernel<<<dim3(2048), dim3(256), 0, stream>>>(inputs, W_in, bias, out);
    esn_scan<<<dim3(B_N), dim3(U_N), 0, stream>>>(W_rec, out);
}